// Round 6
// baseline (1975.809 us; speedup 1.0000x reference)
//
#include <hip/hip_runtime.h>
#include <hip/hip_bf16.h>

typedef __hip_bfloat16 bf16;
typedef short bf16x8 __attribute__((ext_vector_type(8)));
typedef float f32x4 __attribute__((ext_vector_type(4)));

#define DEV __device__ __forceinline__

DEV float bf2f(bf16 v) { return __bfloat162float(v); }
DEV bf16 f2bf(float v) { return __float2bfloat16(v); }
DEV unsigned short bfr(float f) {
  bf16 h = __float2bfloat16(f);
  return *reinterpret_cast<unsigned short*>(&h);
}
DEV float gelu_exact(float x) { return 0.5f * x * (1.0f + erff(x * 0.70710678118654752f)); }

// load a "reference float32" parameter that may physically be bf16 or fp32
DEV float ldw(const void* p, long i, int isb) {
  return isb ? __bfloat162float(((const bf16*)p)[i]) : ((const float*)p)[i];
}

// ---------------- dtype detection + flag constants ----------------
__global__ void k_detect(const unsigned short* __restrict__ u, int* __restrict__ flag) {
  __shared__ int bad;
  if (threadIdx.x == 0) bad = 0;
  __syncthreads();
  for (int i = threadIdx.x; i < 8192; i += 256) {
    int expo = (u[i] >> 7) & 0xFF;
    if (expo >= 138) atomicOr(&bad, 1);
  }
  __syncthreads();
  if (threadIdx.x == 0) *flag = bad ? 0 : 1;
}
__global__ void k_setone(int* p) { *p = 1; }

// ---------------- convert (bf16|fp32) -> fp32 ----------------
__global__ void k_cvt(const void* __restrict__ s, float* __restrict__ d, int n,
                      const int* __restrict__ fl) {
  int isb = *fl;
  int i = blockIdx.x * blockDim.x + threadIdx.x;
  if (i < n) d[i] = ldw(s, i, isb);
}

// convert + transpose conv weights [OC][ICT][9] -> fp32 [ICT][OC][9]
__global__ void k_cvt_trans(const void* __restrict__ s, float* __restrict__ d,
                            int OC, int ICT, int n, const int* __restrict__ fl) {
  int isb = *fl;
  int i = blockIdx.x * blockDim.x + threadIdx.x;
  if (i >= n) return;
  int oc = i / (ICT * 9);
  int r = i - oc * ICT * 9;
  int ic = r / 9, k = r - ic * 9;
  d[((long)ic * OC + oc) * 9 + k] = ldw(s, i, isb);
}

// tokenizer weight [192][49] (at element offset 9408) -> bf16 [192][64] zero-padded
__global__ void k_padtokw(const void* __restrict__ tw, bf16* __restrict__ dst,
                          const int* __restrict__ fl) {
  int isb = *fl;
  int i = blockIdx.x * blockDim.x + threadIdx.x;
  if (i >= 12288) return;
  int n = i >> 6, k = i & 63;
  float v = (k < 49) ? ldw(tw, 9408 + (long)n * 49 + k, isb) : 0.0f;
  dst[i] = f2bf(v);
}

// ---------------- local correlation (level 1), bf16 out, stride 64 (zero-padded) ----------
__global__ void k_corr(const float* __restrict__ F2, bf16* __restrict__ corrT) {
  __shared__ float f1v[128];
  int p = blockIdx.x;          // pixel 0..1023
  int b = blockIdx.y;          // pair 0..1
  int t = threadIdx.x;         // 64 threads
  const float* f1 = F2 + (long)b * 131072;
  const float* f2 = F2 + (long)(b + 1) * 131072;
  f1v[t]      = f1[t * 1024 + p];
  f1v[t + 64] = f1[(t + 64) * 1024 + p];
  __syncthreads();
  long rowo = ((long)b * 1024 + p) * 64;
  if (t < 49) {
    int dy = t / 7 - 3, dx = t % 7 - 3;
    int h = p >> 5, w = p & 31;
    int p2 = (((h - dy) & 31) << 5) | ((w - dx) & 31);
    float s = 0.0f;
    for (int c = 0; c < 128; ++c) s += f1v[c] * f2[c * 1024 + p2];
    corrT[rowo + t] = f2bf(s * 0.08838834764831845f); // 1/sqrt(128)
  } else {
    corrT[rowo + t] = f2bf(0.0f);
  }
}

// ---------------- LayerNorm (D=192), 4 rows/block (1 wave each), bf16 out ----------------
__global__ __launch_bounds__(256) void k_ln(const float* __restrict__ src, bf16* __restrict__ dst,
                     const void* __restrict__ w, long woff,
                     const void* __restrict__ b, long boff,
                     const int* __restrict__ fl) {
  int isb = *fl;
  int row = blockIdx.x * 4 + (threadIdx.x >> 6);
  int t = threadIdx.x & 63;
  const float* s = src + (long)row * 192;
  float e0 = s[t], e1 = s[t + 64], e2 = s[t + 128];
  float sum = e0 + e1 + e2;
  for (int o = 32; o; o >>= 1) sum += __shfl_xor(sum, o);
  float mean = sum * (1.0f / 192.0f);
  float d0 = e0 - mean, d1 = e1 - mean, d2 = e2 - mean;
  float vs = d0 * d0 + d1 * d1 + d2 * d2;
  for (int o = 32; o; o >>= 1) vs += __shfl_xor(vs, o);
  float rstd = rsqrtf(vs * (1.0f / 192.0f) + 1e-5f);
  bf16* o_ = dst + (long)row * 192;
  o_[t]       = f2bf(d0 * rstd * ldw(w, woff + t, isb)       + ldw(b, boff + t, isb));
  o_[t + 64]  = f2bf(d1 * rstd * ldw(w, woff + t + 64, isb)  + ldw(b, boff + t + 64, isb));
  o_[t + 128] = f2bf(d2 * rstd * ldw(w, woff + t + 128, isb) + ldw(b, boff + t + 128, isb));
}

// ---------------- MFMA bf16 GEMM: C(MxN) = A(MxK) @ W(NxK)^T + bias (+res) (+gelu) --------
// BM=BN=64, 256 threads = 4 waves. ABF: A is bf16 (else fp32, converted on stage).
// OUTBF: C written bf16 (else fp32). Requires M%64==0, N%64==0, K%32==0.
template <int ACT, bool HASRES, int ABF, int OUTBF>
__global__ __launch_bounds__(256) void k_gemm_mfma(
    const void* __restrict__ A, const void* __restrict__ W, long woff,
    const void* __restrict__ bias, long boff, const int* __restrict__ flb,
    const float* __restrict__ res, void* __restrict__ C,
    int M, int N, int K, const int* __restrict__ fl) {
  int isb = *fl;
  __shared__ unsigned short Asm[64][40];
  __shared__ unsigned short Wsm[64][40];
  int tid = threadIdx.x;
  int wv = tid >> 6, ln = tid & 63;
  int quad = ln >> 4, l16 = ln & 15;
  int m0 = blockIdx.y * 64, n0 = blockIdx.x * 64;
  int srow = tid >> 2;
  int skc = (tid & 3) * 8;
  f32x4 acc[4] = {};
  for (int k0 = 0; k0 < K; k0 += 32) {
    if (ABF) {
      const unsigned short* ap = (const unsigned short*)A + (long)(m0 + srow) * K + k0 + skc;
      *(uint4*)&Asm[srow][skc] = *(const uint4*)ap;
    } else {
      const float* ap = (const float*)A + (long)(m0 + srow) * K + k0 + skc;
      float4 a0 = *(const float4*)ap;
      float4 a1 = *(const float4*)(ap + 4);
      union { unsigned short u[8]; uint4 v; } pk;
      pk.u[0] = bfr(a0.x); pk.u[1] = bfr(a0.y); pk.u[2] = bfr(a0.z); pk.u[3] = bfr(a0.w);
      pk.u[4] = bfr(a1.x); pk.u[5] = bfr(a1.y); pk.u[6] = bfr(a1.z); pk.u[7] = bfr(a1.w);
      *(uint4*)&Asm[srow][skc] = pk.v;
    }
    {
      long eo = woff + (long)(n0 + srow) * K + k0 + skc;
      if (isb) {
        *(uint4*)&Wsm[srow][skc] = *(const uint4*)((const unsigned short*)W + eo);
      } else {
        const float* wp = (const float*)W + eo;
        float4 w0 = *(const float4*)wp;
        float4 w1 = *(const float4*)(wp + 4);
        union { unsigned short u[8]; uint4 v; } pk;
        pk.u[0] = bfr(w0.x); pk.u[1] = bfr(w0.y); pk.u[2] = bfr(w0.z); pk.u[3] = bfr(w0.w);
        pk.u[4] = bfr(w1.x); pk.u[5] = bfr(w1.y); pk.u[6] = bfr(w1.z); pk.u[7] = bfr(w1.w);
        *(uint4*)&Wsm[srow][skc] = pk.v;
      }
    }
    __syncthreads();
    bf16x8 af = *(const bf16x8*)&Asm[wv * 16 + l16][quad * 8];
#pragma unroll
    for (int nt = 0; nt < 4; ++nt) {
      bf16x8 wf = *(const bf16x8*)&Wsm[nt * 16 + l16][quad * 8];
      acc[nt] = __builtin_amdgcn_mfma_f32_16x16x32_bf16(af, wf, acc[nt], 0, 0, 0);
    }
    __syncthreads();
  }
  int isbb = *flb;
#pragma unroll
  for (int nt = 0; nt < 4; ++nt) {
    int n = n0 + nt * 16 + l16;
    float bv = ldw(bias, boff + n, isbb);
#pragma unroll
    for (int r = 0; r < 4; ++r) {
      int m = m0 + wv * 16 + quad * 4 + r;
      float v = acc[nt][r] + bv;
      if (HASRES) v += res[(long)m * N + n];
      if (ACT == 1) v = gelu_exact(v);
      if (OUTBF) ((bf16*)C)[(long)m * N + n] = f2bf(v);
      else ((float*)C)[(long)m * N + n] = v;
    }
  }
}

// ---------------- fp32 GEMM (kept for the N=2 head output only) ----------------
template <int ACT, bool HASRES>
__global__ __launch_bounds__(256) void k_gemm(const float* __restrict__ A,
                                              const void* __restrict__ W, long woff,
                                              const void* __restrict__ bias, long boff,
                                              const float* __restrict__ res,
                                              float* __restrict__ C, int M, int N, int K, int Kw,
                                              const int* __restrict__ fl) {
  int isb = *fl;
  __shared__ float As[16][132];
  __shared__ float Ws[16][68];
  int tid = threadIdx.x;
  int tx = tid & 15, ty = tid >> 4;
  int m0 = blockIdx.y * 128, n0 = blockIdx.x * 64;
  float acc[8][4] = {};
  for (int k0 = 0; k0 < K; k0 += 16) {
#pragma unroll
    for (int i = 0; i < 2; ++i) {
      int idx4 = tid + i * 256;
      int mm = idx4 >> 2, kc = (idx4 & 3) * 4;
      float4 v = *(const float4*)(A + (long)(m0 + mm) * K + k0 + kc);
      As[kc][mm] = v.x; As[kc + 1][mm] = v.y; As[kc + 2][mm] = v.z; As[kc + 3][mm] = v.w;
    }
#pragma unroll
    for (int i = 0; i < 4; ++i) {
      int idx = tid + i * 256;
      int nn = idx >> 4, kk = idx & 15;
      int gn = n0 + nn, gk = k0 + kk;
      Ws[kk][nn] = (gn < N && gk < Kw) ? ldw(W, woff + (long)gn * Kw + gk, isb) : 0.0f;
    }
    __syncthreads();
#pragma unroll
    for (int kk = 0; kk < 16; ++kk) {
      float4 a0 = *(const float4*)&As[kk][ty * 8];
      float4 a1 = *(const float4*)&As[kk][ty * 8 + 4];
      float4 w4 = *(const float4*)&Ws[kk][tx * 4];
      float av[8] = {a0.x, a0.y, a0.z, a0.w, a1.x, a1.y, a1.z, a1.w};
      float wv[4] = {w4.x, w4.y, w4.z, w4.w};
#pragma unroll
      for (int i = 0; i < 8; ++i)
#pragma unroll
        for (int j = 0; j < 4; ++j) acc[i][j] += av[i] * wv[j];
    }
    __syncthreads();
  }
#pragma unroll
  for (int i = 0; i < 8; ++i) {
    int gm = m0 + ty * 8 + i;
#pragma unroll
    for (int j = 0; j < 4; ++j) {
      int gn = n0 + tx * 4 + j;
      if (gn >= N) continue;
      float v = acc[i][j] + ldw(bias, boff + gn, isb);
      if (HASRES) v += res[(long)gm * N + gn];
      if (ACT == 1) v = gelu_exact(v);
      C[(long)gm * N + gn] = v;
    }
  }
}

// ---------------- MFMA flash attention: Br=64, Bc=64, heads=4, HD=48 (padded 64) ----------
// grid (16 qtiles, 4 heads, 2 pairs), 256 threads = 4 waves; wave owns 16 q-rows.
// qkv bf16 [b][1024][576]; y bf16 [b][1024][192]. Softmax state in registers (per-quad rows).
__global__ __launch_bounds__(256) void k_attn_mfma(const bf16* __restrict__ qkv,
                                                   bf16* __restrict__ y) {
  __shared__ unsigned short Qs[64][72];
  __shared__ unsigned short Ks[64][72];
  __shared__ unsigned short Vs[48][72];
  __shared__ unsigned short Ps[64][72];
  int tid = threadIdx.x;
  int wv = tid >> 6, ln = tid & 63, quad = ln >> 4, l16 = ln & 15;
  int h = blockIdx.y, b = blockIdx.z, q0 = blockIdx.x * 64;
  const unsigned short* qp = (const unsigned short*)qkv + (long)b * 1024 * 576;
  // stage Q (64 rows x 48 dims, zero-pad to 64)
  for (int i = tid; i < 384; i += 256) {
    int r = i / 6, c = i % 6;
    *(uint4*)&Qs[r][c * 8] = *(const uint4*)(qp + (long)(q0 + r) * 576 + h * 48 + c * 8);
  }
  for (int i = tid; i < 128; i += 256) {
    int r = i >> 1, c = 6 + (i & 1);
    uint4 z = {0, 0, 0, 0};
    *(uint4*)&Qs[r][c * 8] = z;
  }
  float m[4] = {-1e30f, -1e30f, -1e30f, -1e30f};
  float l[4] = {0.0f, 0.0f, 0.0f, 0.0f};
  f32x4 accO[3] = {};
  const float SC = 0.14433756729740643f; // 1/sqrt(48)
  for (int kc = 0; kc < 16; ++kc) {
    int k0 = kc * 64;
    for (int i = tid; i < 384; i += 256) {
      int r = i / 6, c = i % 6;
      *(uint4*)&Ks[r][c * 8] = *(const uint4*)(qp + (long)(k0 + r) * 576 + 192 + h * 48 + c * 8);
    }
    for (int i = tid; i < 128; i += 256) {
      int r = i >> 1, c = 6 + (i & 1);
      uint4 z = {0, 0, 0, 0};
      *(uint4*)&Ks[r][c * 8] = z;
    }
    for (int i = tid; i < 3072; i += 256) {  // V transposed: Vs[n][k]
      int k = i / 48, n = i - k * 48;
      Vs[n][k] = qp[(long)(k0 + k) * 576 + 384 + h * 48 + n];
    }
    __syncthreads();
    // S = Q K^T (K-dim 64 = 2 chained MFMAs)
    f32x4 accS[4] = {};
    bf16x8 a0 = *(const bf16x8*)&Qs[wv * 16 + l16][quad * 8];
    bf16x8 a1 = *(const bf16x8*)&Qs[wv * 16 + l16][32 + quad * 8];
#pragma unroll
    for (int ct = 0; ct < 4; ++ct) {
      bf16x8 b0 = *(const bf16x8*)&Ks[ct * 16 + l16][quad * 8];
      bf16x8 b1 = *(const bf16x8*)&Ks[ct * 16 + l16][32 + quad * 8];
      accS[ct] = __builtin_amdgcn_mfma_f32_16x16x32_bf16(a0, b0, accS[ct], 0, 0, 0);
      accS[ct] = __builtin_amdgcn_mfma_f32_16x16x32_bf16(a1, b1, accS[ct], 0, 0, 0);
    }
    // online softmax: rows quad*4+r shared by quad's 16 lanes; butterfly over l16
#pragma unroll
    for (int r = 0; r < 4; ++r) {
      float s0 = accS[0][r] * SC, s1 = accS[1][r] * SC;
      float s2 = accS[2][r] * SC, s3 = accS[3][r] * SC;
      float mx = fmaxf(fmaxf(s0, s1), fmaxf(s2, s3));
      for (int o = 8; o; o >>= 1) mx = fmaxf(mx, __shfl_xor(mx, o));
      float mn = fmaxf(m[r], mx);
      float alpha = __expf(m[r] - mn);
      float p0 = __expf(s0 - mn), p1 = __expf(s1 - mn);
      float p2 = __expf(s2 - mn), p3 = __expf(s3 - mn);
      float rs = p0 + p1 + p2 + p3;
      for (int o = 8; o; o >>= 1) rs += __shfl_xor(rs, o);
      m[r] = mn;
      l[r] = l[r] * alpha + rs;
      accO[0][r] *= alpha; accO[1][r] *= alpha; accO[2][r] *= alpha;
      int prow = wv * 16 + quad * 4 + r;
      Ps[prow][l16]      = bfr(p0);
      Ps[prow][16 + l16] = bfr(p1);
      Ps[prow][32 + l16] = bfr(p2);
      Ps[prow][48 + l16] = bfr(p3);
    }
    // O += P V  (Ps rows are wave-private; Vs staged this chunk)
    bf16x8 pf0 = *(const bf16x8*)&Ps[wv * 16 + l16][quad * 8];
    bf16x8 pf1 = *(const bf16x8*)&Ps[wv * 16 + l16][32 + quad * 8];
#pragma unroll
    for (int ct = 0; ct < 3; ++ct) {
      bf16x8 v0 = *(const bf16x8*)&Vs[ct * 16 + l16][quad * 8];
      bf16x8 v1 = *(const bf16x8*)&Vs[ct * 16 + l16][32 + quad * 8];
      accO[ct] = __builtin_amdgcn_mfma_f32_16x16x32_bf16(pf0, v0, accO[ct], 0, 0, 0);
      accO[ct] = __builtin_amdgcn_mfma_f32_16x16x32_bf16(pf1, v1, accO[ct], 0, 0, 0);
    }
    __syncthreads();
  }
  unsigned short* yp = (unsigned short*)y + (long)b * 1024 * 192;
#pragma unroll
  for (int r = 0; r < 4; ++r) {
    float inv = 1.0f / l[r];
    int row = q0 + wv * 16 + quad * 4 + r;
#pragma unroll
    for (int ct = 0; ct < 3; ++ct)
      yp[(long)row * 192 + h * 48 + ct * 16 + l16] = bfr(accO[ct][r] * inv);
  }
}

// ---------------- EMA: x[pair1] = 0.8*x[pair1] + 0.2*x[pair0] ----------------
__global__ void k_ema(float* __restrict__ x) {
  int i = blockIdx.x * blockDim.x + threadIdx.x;
  if (i < 196608) x[196608 + i] = 0.8f * x[196608 + i] + 0.2f * x[i];
}

// ---------------- fv (2048x2) -> flow [b][2][1024] ----------------
__global__ void k_fv2flow(const float* __restrict__ fv, float* __restrict__ cur) {
  int i = blockIdx.x * blockDim.x + threadIdx.x;
  if (i < 4096) {
    int b = i >> 11, r = i & 2047;
    int c = r >> 10, p = r & 1023;
    cur[i] = fv[(long)(b * 1024 + p) * 2 + c];
  }
}

// ---------------- warp (bilinear, border clamp); img for pair b is imgbase[(b+1)] --------
__global__ void k_warp(const float* __restrict__ imgbase, const float* __restrict__ flow,
                       float* __restrict__ out, int C, int H, int W) {
  int HW = H * W;
  int per = C * HW;
  int i = blockIdx.x * blockDim.x + threadIdx.x;
  if (i >= 2 * per) return;
  int b = i / per;
  int rem = i - b * per;
  int c = rem / HW;
  int p = rem - c * HW;
  int h = p / W, w = p - h * W;
  const float* img = imgbase + (long)(b + 1) * per;
  const float* fl = flow + (long)b * 2 * HW;
  float x = fminf(fmaxf((float)w + fl[p], 0.0f), (float)(W - 1));
  float yy = fminf(fmaxf((float)h + fl[HW + p], 0.0f), (float)(H - 1));
  int x0 = (int)floorf(x), y0 = (int)floorf(yy);
  int x1 = min(x0 + 1, W - 1), y1 = min(y0 + 1, H - 1);
  float wx = x - (float)x0, wy = yy - (float)y0;
  const float* ic = img + (long)c * HW;
  float v00 = ic[y0 * W + x0], v01 = ic[y0 * W + x1];
  float v10 = ic[y1 * W + x0], v11 = ic[y1 * W + x1];
  out[i] = v00 * (1 - wx) * (1 - wy) + v01 * wx * (1 - wy) + v10 * (1 - wx) * wy + v11 * wx * wy;
}

// ---------------- 3x3 conv phase 1: partial sums over an input-channel split -----------
template <int OCG>
__global__ __launch_bounds__(256) void k_conv_part(
    const float* __restrict__ s0, int c0, long s0bs,
    const float* __restrict__ s1, int c1, long s1bs,
    const float* __restrict__ s2, int c2, long s2bs,
    const float* __restrict__ wT, int OC,
    float* __restrict__ pa, long Sa, int na, float* __restrict__ pb,
    int H, int W, int NS) {
  __shared__ float T[8][18][20];
  int tid = threadIdx.x;
  int nTx = W >> 4;
  int ty0 = (blockIdx.x / nTx) << 4, tx0 = (blockIdx.x % nTx) << 4;
  int oc0 = blockIdx.y * OCG;
  int z = blockIdx.z;
  int b = z / NS, s = z - b * NS;
  int ICT = c0 + c1 + c2;
  int csz = (ICT + NS - 1) / NS;
  int g0 = s * csz, g1 = min(ICT, g0 + csz);
  float acc[OCG] = {};
  int ly = tid >> 4, lx = tid & 15;
  const float* sp0 = s0 + (long)b * s0bs;
  const float* sp1 = s1 ? s1 + (long)b * s1bs : nullptr;
  const float* sp2 = s2 ? s2 + (long)b * s2bs : nullptr;
  for (int gc = g0; gc < g1; gc += 8) {
    int nb = min(8, g1 - gc);
    for (int i = tid; i < nb * 324; i += 256) {
      int bch = i / 324, w2 = i - bch * 324;
      int rr = w2 / 18, cc = w2 - rr * 18;
      int yy = ty0 - 1 + rr, xx = tx0 - 1 + cc;
      int gch = gc + bch;
      const float* sp; int lc;
      if (gch < c0) { sp = sp0; lc = gch; }
      else if (gch < c0 + c1) { sp = sp1; lc = gch - c0; }
      else { sp = sp2; lc = gch - c0 - c1; }
      T[bch][rr][cc] = (yy >= 0 && yy < H && xx >= 0 && xx < W)
                           ? sp[(long)lc * H * W + yy * W + xx] : 0.0f;
    }
    __syncthreads();
    for (int j = 0; j < nb; ++j) {
      float t00 = T[j][ly][lx],     t01 = T[j][ly][lx + 1],     t02 = T[j][ly][lx + 2];
      float t10 = T[j][ly + 1][lx], t11 = T[j][ly + 1][lx + 1], t12 = T[j][ly + 1][lx + 2];
      float t20 = T[j][ly + 2][lx], t21 = T[j][ly + 2][lx + 1], t22 = T[j][ly + 2][lx + 2];
      const float* wp = wT + ((long)(gc + j) * OC + oc0) * 9;
#pragma unroll
      for (int o = 0; o < OCG; ++o) {
        const float* w9 = wp + o * 9;
        acc[o] += t00 * w9[0] + t01 * w9[1] + t02 * w9[2]
                + t10 * w9[3] + t11 * w9[4] + t12 * w9[5]
                + t20 * w9[6] + t21 * w9[7] + t22 * w9[8];
      }
    }
    __syncthreads();
  }
  float* base = (s < na) ? pa + (long)s * Sa : pb + (long)(s - na) * Sa;
  long p = (long)(ty0 + ly) * W + (tx0 + lx);
#pragma unroll
  for (int o = 0; o < OCG; ++o)
    base[((long)b * OC + (oc0 + o)) * (long)(H * W) + p] = acc[o];
}

// phase 2: out = [gelu](bias + sum of partial chunks) [+ res]
__global__ void k_conv_fin(const float* __restrict__ pa, long Sa, int na,
                           const float* __restrict__ pb, int nb2,
                           const float* __restrict__ bias, const float* __restrict__ res,
                           float* __restrict__ out, int OC, int HW, int act, int n) {
  int i = blockIdx.x * blockDim.x + threadIdx.x;
  if (i >= n) return;
  int oc = (i / HW) % OC;
  float v = bias[oc];
  for (int s = 0; s < na; ++s) v += pa[(long)s * Sa + i];
  for (int s = 0; s < nb2; ++s) v += pb[(long)s * Sa + i];
  if (act) v = gelu_exact(v);
  if (res) v += res[i];
  out[i] = v;
}

// ---------------- 2x align-corners bilinear upsample ----------------
__global__ void k_upsample(const float* __restrict__ in, float* __restrict__ out) {
  int i = blockIdx.x * blockDim.x + threadIdx.x;
  if (i >= 2 * 2 * 64 * 64) return;
  int p = i & 4095;
  int bc = i >> 12;
  int oy = p >> 6, ox = p & 63;
  float sx = ox * (31.0f / 63.0f), sy = oy * (31.0f / 63.0f);
  int x0 = (int)sx, y0 = (int)sy;
  int x1 = min(x0 + 1, 31), y1 = min(y0 + 1, 31);
  float wx = sx - x0, wy = sy - y0;
  const float* ic = in + (long)bc * 1024;
  out[i] = ic[y0 * 32 + x0] * (1 - wx) * (1 - wy) + ic[y0 * 32 + x1] * wx * (1 - wy)
         + ic[y1 * 32 + x0] * (1 - wx) * wy      + ic[y1 * 32 + x1] * wx * wy;
}

// ---------------- final write (fp32 -> bf16|fp32 per detected dtype) ----------------
__global__ void k_out(const float* __restrict__ cur2, void* __restrict__ out,
                      const int* __restrict__ fl) {
  int isb = *fl;
  int i = blockIdx.x * blockDim.x + threadIdx.x;
  if (i < 16384) {
    if (isb) ((bf16*)out)[i] = f2bf(cur2[i]);
    else ((float*)out)[i] = cur2[i];
  }
}

extern "C" void kernel_launch(void* const* d_in, const int* in_sizes, int n_in,
                              void* d_out, int out_size, void* d_ws, size_t ws_size,
                              hipStream_t stream) {
  const void* feats_l1 = d_in[0];
  const void* feats_l2 = d_in[1];
  const void* tok_w = d_in[3];
  const void* tok_b = d_in[4];
  const void* lcm_ln1_w = d_in[5];
  const void* lcm_ln1_b = d_in[6];
  const void* lcm_in_w  = d_in[7];
  const void* lcm_in_b  = d_in[8];
  const void* lcm_out_w = d_in[9];
  const void* lcm_out_b = d_in[10];
  const void* lcm_ln2_w = d_in[11];
  const void* lcm_ln2_b = d_in[12];
  const void* lcm_mlp_w1 = d_in[13];
  const void* lcm_mlp_b1 = d_in[14];
  const void* lcm_mlp_w2 = d_in[15];
  const void* lcm_mlp_b2 = d_in[16];
  const void* gtr_ln1_w = d_in[17];
  const void* gtr_ln1_b = d_in[18];
  const void* gtr_in_w  = d_in[19];
  const void* gtr_in_b  = d_in[20];
  const void* gtr_out_w = d_in[21];
  const void* gtr_out_b = d_in[22];
  const void* gtr_ln2_w = d_in[23];
  const void* gtr_ln2_b = d_in[24];
  const void* gtr_mlp_w1 = d_in[25];
  const void* gtr_mlp_b1 = d_in[26];
  const void* gtr_mlp_w2 = d_in[27];
  const void* gtr_mlp_b2 = d_in[28];
  const void* head_w1 = d_in[29];
  const void* head_b1 = d_in[30];
  const void* head_w2 = d_in[31];
  const void* head_b2 = d_in[32];
  const void* ref1_w1 = d_in[33];
  const void* ref1_b1 = d_in[34];
  const void* ref1_w2 = d_in[35];
  const void* ref1_b2 = d_in[36];
  const void* ref0_w1 = d_in[37];
  const void* ref0_b1 = d_in[38];
  const void* ref0_w2 = d_in[39];
  const void* ref0_b2 = d_in[40];
  (void)ws_size; (void)n_in; (void)in_sizes; (void)out_size;

  // ---- workspace layout (fp32; ~17.3 MB, unchanged budget) ----
  int* flag = (int*)d_ws;
  int* oneflag = (int*)d_ws + 2;
  float* wsf = (float*)d_ws;
  float* F2  = wsf + 16;              // 393216
  float* F1  = F2 + 393216;           // 786432
  float* x   = F1 + 786432;           // 393216 (fp32 residual stream)
  float* ta  = x + 393216;            // 393216 (bf16 LN out alias; fp32 head-hidden later)
  float* yb  = ta + 393216;           // 393216 (bf16 attention out alias)
  float* big = yb + 393216;           // 1572864: corrT/qkv/hid (bf16 aliases) | decoder scratch
  float* fv  = big + 1572864;         // 4096
  float* cur = fv + 4096;             // 4096   [2][2][1024]
  float* cur2 = cur + 4096;           // 16384  [2][2][4096]
  float* cwT1a = cur2 + 16384;        // 297216 : ref1_w1 fp32 transposed [258][128][9]
  float* cb1a  = cwT1a + 297216;      // 128
  float* cwT1b = cb1a + 128;          // 2304   : ref1_w2 [128][2][9]
  float* cb1b  = cwT1b + 2304;        // 16 (2 used)
  float* cwT0a = cb1b + 16;           // 74880  : ref0_w1 [130][64][9]
  float* cb0a  = cwT0a + 74880;       // 64
  float* cwT0b = cb0a + 64;           // 1152   : ref0_w2 [64][2][9]
  float* cb0b  = cwT0b + 1152;        // 16 (2 used)
  bf16* wtok   = (bf16*)(cb0b + 16);  // 12288 bf16: padded tokenizer W [192][64]
  bf16* tb      = (bf16*)ta;          // LN output, 2048x192 bf16
  bf16* ybb     = (bf16*)yb;          // attention out, 2048x192 bf16
  bf16* corrTb  = (bf16*)big;         // 2048x64 bf16
  bf16* qkvbb   = (bf16*)big;         // 2048x576 bf16
  bf16* hidb    = (bf16*)big;         // 2048x768 bf16 (qkv dead by then)
  float* wp1  = big;                  // [2][128][1024]
  float* mid1 = big + 262144;         // [2][128][1024]
  float* wp0  = big;                  // [2][64][4096]
  float* mid0 = big + 524288;         // [2][64][4096]
  float* bigtail = big + 1048576;     // 3rd l0-conv1 partial chunk
  float* p1b  = big + 524288;         // l1-conv2 partials

  k_detect<<<1, 256, 0, stream>>>((const unsigned short*)feats_l1, flag);
  k_setone<<<1, 1, 0, stream>>>(oneflag);
  k_cvt<<<1536, 256, 0, stream>>>(feats_l2, F2, 393216, flag);
  k_cvt<<<3072, 256, 0, stream>>>(feats_l1, F1, 786432, flag);
  k_cvt_trans<<<1161, 256, 0, stream>>>(ref1_w1, cwT1a, 128, 258, 297216, flag);
  k_cvt<<<1, 256, 0, stream>>>(ref1_b1, cb1a, 128, flag);
  k_cvt_trans<<<9, 256, 0, stream>>>(ref1_w2, cwT1b, 2, 128, 2304, flag);
  k_cvt<<<1, 256, 0, stream>>>(ref1_b2, cb1b, 2, flag);
  k_cvt_trans<<<293, 256, 0, stream>>>(ref0_w1, cwT0a, 64, 130, 74880, flag);
  k_cvt<<<1, 256, 0, stream>>>(ref0_b1, cb0a, 64, flag);
  k_cvt_trans<<<5, 256, 0, stream>>>(ref0_w2, cwT0b, 2, 64, 1152, flag);
  k_cvt<<<1, 256, 0, stream>>>(ref0_b2, cb0b, 2, flag);
  k_padtokw<<<48, 256, 0, stream>>>(tok_w, wtok, flag);

  // ---- tokens (level 1 only): corr (bf16, K padded 64) then tokenizer GEMM (MFMA) ----
  k_corr<<<dim3(1024, 2), 64, 0, stream>>>(F2, corrTb);
  k_gemm_mfma<0, false, 1, 0><<<dim3(3, 32), 256, 0, stream>>>(
      corrTb, wtok, 0, tok_b, 192, flag, nullptr, x, 2048, 192, 64, oneflag);

  auto run_block = [&](const void* ln1w, long o1, const void* ln1b, long o2,
                       const void* inw, long o3, const void* inb, long o4,
                       const void* ow, long o5, const void* ob, long o6,
                       const void* ln2w, long o7, const void* ln2b, long o8,
                       const void* w1, long o9, const void* b1, long o10,
                       const void* w2, long o11, const void* b2, long o12) {
    k_ln<<<512, 256, 0, stream>>>(x, tb, ln1w, o1, ln1b, o2, flag);
    k_gemm_mfma<0, false, 1, 1><<<dim3(9, 32), 256, 0, stream>>>(
        tb, inw, o3, inb, o4, flag, nullptr, qkvbb, 2048, 576, 192, flag);
    k_attn_mfma<<<dim3(16, 4, 2), 256, 0, stream>>>(qkvbb, ybb);
    k_gemm_mfma<0, true, 1, 0><<<dim3(3, 32), 256, 0, stream>>>(
        ybb, ow, o5, ob, o6, flag, x, x, 2048, 192, 192, flag);
    k_ln<<<512, 256, 0, stream>>>(x, tb, ln2w, o7, ln2b, o8, flag);
    k_gemm_mfma<1, false, 1, 1><<<dim3(12, 32), 256, 0, stream>>>(
        tb, w1, o9, b1, o10, flag, nullptr, hidb, 2048, 768, 192, flag);
    k_gemm_mfma<0, true, 1, 0><<<dim3(3, 32), 256, 0, stream>>>(
        hidb, w2, o11, b2, o12, flag, x, x, 2048, 192, 768, flag);
  };

  // ---- LCM: 6 blocks, both pairs batched ----
  for (int i = 0; i < 6; ++i) {
    run_block(lcm_ln1_w, (long)i * 192, lcm_ln1_b, (long)i * 192,
              lcm_in_w, (long)i * 110592, lcm_in_b, (long)i * 576,
              lcm_out_w, (long)i * 36864, lcm_out_b, (long)i * 192,
              lcm_ln2_w, (long)i * 192, lcm_ln2_b, (long)i * 192,
              lcm_mlp_w1, (long)i * 147456, lcm_mlp_b1, (long)i * 768,
              lcm_mlp_w2, (long)i * 147456, lcm_mlp_b2, (long)i * 192);
  }
  k_ema<<<768, 256, 0, stream>>>(x);

  // ---- GTR: 2 blocks ----
  for (int i = 0; i < 2; ++i) {
    run_block(gtr_ln1_w, (long)i * 192, gtr_ln1_b, (long)i * 192,
              gtr_in_w, (long)i * 110592, gtr_in_b, (long)i * 576,
              gtr_out_w, (long)i * 36864, gtr_out_b, (long)i * 192,
              gtr_ln2_w, (long)i * 192, gtr_ln2_b, (long)i * 192,
              gtr_mlp_w1, (long)i * 147456, gtr_mlp_b1, (long)i * 768,
              gtr_mlp_w2, (long)i * 147456, gtr_mlp_b2, (long)i * 192);
  }

  // ---- head -> coarse flow ----
  k_gemm_mfma<1, false, 0, 0><<<dim3(3, 32), 256, 0, stream>>>(
      x, head_w1, 0, head_b1, 0, flag, nullptr, ta, 2048, 192, 192, flag);
  k_gemm<0, false><<<dim3(1, 16), 256, 0, stream>>>(ta, head_w2, 0, head_b2, 0, nullptr, fv,
                                                    2048, 2, 192, 192, flag);
  k_fv2flow<<<16, 256, 0, stream>>>(fv, cur);

  // ---- decoder level 1 (32x32, feats_l2); IC=258 split NS=4 ----
  for (int it = 0; it < 4; ++it) {
    k_warp<<<1024, 256, 0, stream>>>(F2, cur, wp1, 128, 32, 32);
    k_conv_part<8><<<dim3(4, 16, 8), 256, 0, stream>>>(
        F2, 128, 131072, cur, 2, 2048, wp1, 128, 131072,
        cwT1a, 128, x, 262144, 4, nullptr, 32, 32, 4);
    k_conv_fin<<<1024, 256, 0, stream>>>(x, 262144, 4, nullptr, 0, cb1a, nullptr,
                                         mid1, 128, 1024, 1, 262144);
    k_conv_part<2><<<dim3(4, 1, 32), 256, 0, stream>>>(
        mid1, 128, 131072, nullptr, 0, 0, nullptr, 0, 0,
        cwT1b, 2, p1b, 4096, 16, nullptr, 32, 32, 16);
    k_conv_fin<<<32, 256, 0, stream>>>(p1b, 4096, 16, nullptr, 0, cb1b, cur,
                                       cur, 2, 1024, 0, 8192);
  }
  k_upsample<<<64, 256, 0, stream>>>(cur, cur2);

  // ---- decoder level 0 (64x64, feats_l1); IC=130 split NS=3 ----
  for (int it = 0; it < 4; ++it) {
    k_warp<<<2048, 256, 0, stream>>>(F1, cur2, wp0, 64, 64, 64);
    k_conv_part<8><<<dim3(16, 8, 6), 256, 0, stream>>>(
        F1, 64, 262144, cur2, 2, 8192, wp0, 64, 262144,
        cwT0a, 64, x, 524288, 2, bigtail, 64, 64, 3);
    k_conv_fin<<<2048, 256, 0, stream>>>(x, 524288, 2, bigtail, 1, cb0a, nullptr,
                                         mid0, 64, 4096, 1, 524288);
    k_conv_part<2><<<dim3(16, 1, 16), 256, 0, stream>>>(
        mid0, 64, 262144, nullptr, 0, 0, nullptr, 0, 0,
        cwT0b, 2, x, 16384, 8, nullptr, 64, 64, 8);
    k_conv_fin<<<128, 256, 0, stream>>>(x, 16384, 8, nullptr, 0, cb0b, cur2,
                                        cur2, 2, 4096, 0, 32768);
  }

  k_out<<<64, 256, 0, stream>>>(cur2, d_out, flag);
}

// Round 7
// 1530.622 us; speedup vs baseline: 1.2909x; 1.2909x over previous
//
#include <hip/hip_runtime.h>
#include <hip/hip_bf16.h>

typedef __hip_bfloat16 bf16;
typedef short bf16x8 __attribute__((ext_vector_type(8)));
typedef float f32x4 __attribute__((ext_vector_type(4)));

#define DEV __device__ __forceinline__

DEV float bf2f(bf16 v) { return __bfloat162float(v); }
DEV bf16 f2bf(float v) { return __float2bfloat16(v); }
DEV unsigned short bfr(float f) {
  bf16 h = __float2bfloat16(f);
  return *reinterpret_cast<unsigned short*>(&h);
}
DEV float gelu_exact(float x) { return 0.5f * x * (1.0f + erff(x * 0.70710678118654752f)); }

// load a "reference float32" parameter that may physically be bf16 or fp32
DEV float ldw(const void* p, long i, int isb) {
  return isb ? __bfloat162float(((const bf16*)p)[i]) : ((const float*)p)[i];
}

// ---------------- dtype detection + flag constants ----------------
__global__ void k_detect(const unsigned short* __restrict__ u, int* __restrict__ flag) {
  __shared__ int bad;
  if (threadIdx.x == 0) bad = 0;
  __syncthreads();
  for (int i = threadIdx.x; i < 8192; i += 256) {
    int expo = (u[i] >> 7) & 0xFF;
    if (expo >= 138) atomicOr(&bad, 1);
  }
  __syncthreads();
  if (threadIdx.x == 0) *flag = bad ? 0 : 1;
}
__global__ void k_setone(int* p) { *p = 1; }

// ---------------- convert (bf16|fp32) -> fp32 ----------------
__global__ void k_cvt(const void* __restrict__ s, float* __restrict__ d, int n,
                      const int* __restrict__ fl) {
  int isb = *fl;
  int i = blockIdx.x * blockDim.x + threadIdx.x;
  if (i < n) d[i] = ldw(s, i, isb);
}

// convert + transpose conv weights [OC][ICT][9] -> fp32 [ICT][OC][9]
__global__ void k_cvt_trans(const void* __restrict__ s, float* __restrict__ d,
                            int OC, int ICT, int n, const int* __restrict__ fl) {
  int isb = *fl;
  int i = blockIdx.x * blockDim.x + threadIdx.x;
  if (i >= n) return;
  int oc = i / (ICT * 9);
  int r = i - oc * ICT * 9;
  int ic = r / 9, k = r - ic * 9;
  d[((long)ic * OC + oc) * 9 + k] = ldw(s, i, isb);
}

// tokenizer weight [192][49] (at element offset 9408) -> bf16 [192][64] zero-padded
__global__ void k_padtokw(const void* __restrict__ tw, bf16* __restrict__ dst,
                          const int* __restrict__ fl) {
  int isb = *fl;
  int i = blockIdx.x * blockDim.x + threadIdx.x;
  if (i >= 12288) return;
  int n = i >> 6, k = i & 63;
  float v = (k < 49) ? ldw(tw, 9408 + (long)n * 49 + k, isb) : 0.0f;
  dst[i] = f2bf(v);
}

// ---------------- local correlation (level 1), bf16 out, stride 64 (zero-padded) ----------
__global__ void k_corr(const float* __restrict__ F2, bf16* __restrict__ corrT) {
  __shared__ float f1v[128];
  int p = blockIdx.x;          // pixel 0..1023
  int b = blockIdx.y;          // pair 0..1
  int t = threadIdx.x;         // 64 threads
  const float* f1 = F2 + (long)b * 131072;
  const float* f2 = F2 + (long)(b + 1) * 131072;
  f1v[t]      = f1[t * 1024 + p];
  f1v[t + 64] = f1[(t + 64) * 1024 + p];
  __syncthreads();
  long rowo = ((long)b * 1024 + p) * 64;
  if (t < 49) {
    int dy = t / 7 - 3, dx = t % 7 - 3;
    int h = p >> 5, w = p & 31;
    int p2 = (((h - dy) & 31) << 5) | ((w - dx) & 31);
    float s = 0.0f;
    for (int c = 0; c < 128; ++c) s += f1v[c] * f2[c * 1024 + p2];
    corrT[rowo + t] = f2bf(s * 0.08838834764831845f); // 1/sqrt(128)
  } else {
    corrT[rowo + t] = f2bf(0.0f);
  }
}

// ---------------- LayerNorm (D=192), 4 rows/block (1 wave each), bf16 out ----------------
__global__ __launch_bounds__(256) void k_ln(const float* __restrict__ src, bf16* __restrict__ dst,
                     const void* __restrict__ w, long woff,
                     const void* __restrict__ b, long boff,
                     const int* __restrict__ fl) {
  int isb = *fl;
  int row = blockIdx.x * 4 + (threadIdx.x >> 6);
  int t = threadIdx.x & 63;
  const float* s = src + (long)row * 192;
  float e0 = s[t], e1 = s[t + 64], e2 = s[t + 128];
  float sum = e0 + e1 + e2;
  for (int o = 32; o; o >>= 1) sum += __shfl_xor(sum, o);
  float mean = sum * (1.0f / 192.0f);
  float d0 = e0 - mean, d1 = e1 - mean, d2 = e2 - mean;
  float vs = d0 * d0 + d1 * d1 + d2 * d2;
  for (int o = 32; o; o >>= 1) vs += __shfl_xor(vs, o);
  float rstd = rsqrtf(vs * (1.0f / 192.0f) + 1e-5f);
  bf16* o_ = dst + (long)row * 192;
  o_[t]       = f2bf(d0 * rstd * ldw(w, woff + t, isb)       + ldw(b, boff + t, isb));
  o_[t + 64]  = f2bf(d1 * rstd * ldw(w, woff + t + 64, isb)  + ldw(b, boff + t + 64, isb));
  o_[t + 128] = f2bf(d2 * rstd * ldw(w, woff + t + 128, isb) + ldw(b, boff + t + 128, isb));
}

// ---------------- MFMA bf16 GEMM: C(MxN) = A(MxK) @ W(NxK)^T + bias (+res) (+gelu) --------
template <int ACT, bool HASRES, int ABF, int OUTBF>
__global__ __launch_bounds__(256) void k_gemm_mfma(
    const void* __restrict__ A, const void* __restrict__ W, long woff,
    const void* __restrict__ bias, long boff, const int* __restrict__ flb,
    const float* __restrict__ res, void* __restrict__ C,
    int M, int N, int K, const int* __restrict__ fl) {
  int isb = *fl;
  __shared__ unsigned short Asm[64][40];
  __shared__ unsigned short Wsm[64][40];
  int tid = threadIdx.x;
  int wv = tid >> 6, ln = tid & 63;
  int quad = ln >> 4, l16 = ln & 15;
  int m0 = blockIdx.y * 64, n0 = blockIdx.x * 64;
  int srow = tid >> 2;
  int skc = (tid & 3) * 8;
  f32x4 acc[4] = {};
  for (int k0 = 0; k0 < K; k0 += 32) {
    if (ABF) {
      const unsigned short* ap = (const unsigned short*)A + (long)(m0 + srow) * K + k0 + skc;
      *(uint4*)&Asm[srow][skc] = *(const uint4*)ap;
    } else {
      const float* ap = (const float*)A + (long)(m0 + srow) * K + k0 + skc;
      float4 a0 = *(const float4*)ap;
      float4 a1 = *(const float4*)(ap + 4);
      union { unsigned short u[8]; uint4 v; } pk;
      pk.u[0] = bfr(a0.x); pk.u[1] = bfr(a0.y); pk.u[2] = bfr(a0.z); pk.u[3] = bfr(a0.w);
      pk.u[4] = bfr(a1.x); pk.u[5] = bfr(a1.y); pk.u[6] = bfr(a1.z); pk.u[7] = bfr(a1.w);
      *(uint4*)&Asm[srow][skc] = pk.v;
    }
    {
      long eo = woff + (long)(n0 + srow) * K + k0 + skc;
      if (isb) {
        *(uint4*)&Wsm[srow][skc] = *(const uint4*)((const unsigned short*)W + eo);
      } else {
        const float* wp = (const float*)W + eo;
        float4 w0 = *(const float4*)wp;
        float4 w1 = *(const float4*)(wp + 4);
        union { unsigned short u[8]; uint4 v; } pk;
        pk.u[0] = bfr(w0.x); pk.u[1] = bfr(w0.y); pk.u[2] = bfr(w0.z); pk.u[3] = bfr(w0.w);
        pk.u[4] = bfr(w1.x); pk.u[5] = bfr(w1.y); pk.u[6] = bfr(w1.z); pk.u[7] = bfr(w1.w);
        *(uint4*)&Wsm[srow][skc] = pk.v;
      }
    }
    __syncthreads();
    bf16x8 af = *(const bf16x8*)&Asm[wv * 16 + l16][quad * 8];
#pragma unroll
    for (int nt = 0; nt < 4; ++nt) {
      bf16x8 wf = *(const bf16x8*)&Wsm[nt * 16 + l16][quad * 8];
      acc[nt] = __builtin_amdgcn_mfma_f32_16x16x32_bf16(af, wf, acc[nt], 0, 0, 0);
    }
    __syncthreads();
  }
  int isbb = *flb;
#pragma unroll
  for (int nt = 0; nt < 4; ++nt) {
    int n = n0 + nt * 16 + l16;
    float bv = ldw(bias, boff + n, isbb);
#pragma unroll
    for (int r = 0; r < 4; ++r) {
      int m = m0 + wv * 16 + quad * 4 + r;
      float v = acc[nt][r] + bv;
      if (HASRES) v += res[(long)m * N + n];
      if (ACT == 1) v = gelu_exact(v);
      if (OUTBF) ((bf16*)C)[(long)m * N + n] = f2bf(v);
      else ((float*)C)[(long)m * N + n] = v;
    }
  }
}

// ---------------- fp32 GEMM (kept for the N=2 head output only) ----------------
template <int ACT, bool HASRES>
__global__ __launch_bounds__(256) void k_gemm(const float* __restrict__ A,
                                              const void* __restrict__ W, long woff,
                                              const void* __restrict__ bias, long boff,
                                              const float* __restrict__ res,
                                              float* __restrict__ C, int M, int N, int K, int Kw,
                                              const int* __restrict__ fl) {
  int isb = *fl;
  __shared__ float As[16][132];
  __shared__ float Ws[16][68];
  int tid = threadIdx.x;
  int tx = tid & 15, ty = tid >> 4;
  int m0 = blockIdx.y * 128, n0 = blockIdx.x * 64;
  float acc[8][4] = {};
  for (int k0 = 0; k0 < K; k0 += 16) {
#pragma unroll
    for (int i = 0; i < 2; ++i) {
      int idx4 = tid + i * 256;
      int mm = idx4 >> 2, kc = (idx4 & 3) * 4;
      float4 v = *(const float4*)(A + (long)(m0 + mm) * K + k0 + kc);
      As[kc][mm] = v.x; As[kc + 1][mm] = v.y; As[kc + 2][mm] = v.z; As[kc + 3][mm] = v.w;
    }
#pragma unroll
    for (int i = 0; i < 4; ++i) {
      int idx = tid + i * 256;
      int nn = idx >> 4, kk = idx & 15;
      int gn = n0 + nn, gk = k0 + kk;
      Ws[kk][nn] = (gn < N && gk < Kw) ? ldw(W, woff + (long)gn * Kw + gk, isb) : 0.0f;
    }
    __syncthreads();
#pragma unroll
    for (int kk = 0; kk < 16; ++kk) {
      float4 a0 = *(const float4*)&As[kk][ty * 8];
      float4 a1 = *(const float4*)&As[kk][ty * 8 + 4];
      float4 w4 = *(const float4*)&Ws[kk][tx * 4];
      float av[8] = {a0.x, a0.y, a0.z, a0.w, a1.x, a1.y, a1.z, a1.w};
      float wv[4] = {w4.x, w4.y, w4.z, w4.w};
#pragma unroll
      for (int i = 0; i < 8; ++i)
#pragma unroll
        for (int j = 0; j < 4; ++j) acc[i][j] += av[i] * wv[j];
    }
    __syncthreads();
  }
#pragma unroll
  for (int i = 0; i < 8; ++i) {
    int gm = m0 + ty * 8 + i;
#pragma unroll
    for (int j = 0; j < 4; ++j) {
      int gn = n0 + tx * 4 + j;
      if (gn >= N) continue;
      float v = acc[i][j] + ldw(bias, boff + gn, isb);
      if (HASRES) v += res[(long)gm * N + gn];
      if (ACT == 1) v = gelu_exact(v);
      C[(long)gm * N + gn] = v;
    }
  }
}

// ---------------- V transpose: vt[b][h][d][row] = qkv[b][row][384+h*48+d] ----------------
__global__ __launch_bounds__(256) void k_vt(const bf16* __restrict__ qkv,
                                            bf16* __restrict__ vt) {
  __shared__ unsigned short T[64][56];
  int h = blockIdx.y, b = blockIdx.z;
  int r0 = blockIdx.x * 64;
  const unsigned short* qp = (const unsigned short*)qkv + (long)b * 1024 * 576 + 384 + h * 48;
  for (int i = threadIdx.x; i < 384; i += 256) {
    int r = i / 6, c = i % 6;
    *(uint4*)&T[r][c * 8] = *(const uint4*)(qp + (long)(r0 + r) * 576 + c * 8);
  }
  __syncthreads();
  unsigned short* vp = (unsigned short*)vt + ((long)(b * 4 + h) * 48) * 1024 + r0;
  for (int i = threadIdx.x; i < 384; i += 256) {
    int d = i >> 3, c = i & 7;
    union { unsigned short u[8]; uint4 v; } pk;
#pragma unroll
    for (int j = 0; j < 8; ++j) pk.u[j] = T[c * 8 + j][d];
    *(uint4*)(vp + (long)d * 1024 + c * 8) = pk.v;
  }
}

// ---------------- MFMA flash attention, split-K (2 splits of 8 chunks) -------------------
// grid (32,4,2): qtile = bx>>1, split = bx&1; 256 threads = 4 waves; wave owns 16 q-rows.
// Writes RAW partials: opart[((s*2+b)*4+h)*1024+row][48], ml[..][2] = {m, l}.
__global__ __launch_bounds__(256) void k_attn_mfma(const bf16* __restrict__ qkv,
                                                   const bf16* __restrict__ vt,
                                                   float* __restrict__ opart,
                                                   float* __restrict__ ml) {
  __shared__ unsigned short Qs[64][72];
  __shared__ unsigned short Ks[64][72];
  __shared__ unsigned short Vs[48][72];
  __shared__ unsigned short Ps[64][72];
  int tid = threadIdx.x;
  int wv = tid >> 6, ln = tid & 63, quad = ln >> 4, l16 = ln & 15;
  int h = blockIdx.y, b = blockIdx.z;
  int qt = blockIdx.x >> 1, s = blockIdx.x & 1;
  int q0 = qt * 64;
  const unsigned short* qp = (const unsigned short*)qkv + (long)b * 1024 * 576;
  const unsigned short* vp = (const unsigned short*)vt + ((long)(b * 4 + h) * 48) * 1024;
  for (int i = tid; i < 384; i += 256) {
    int r = i / 6, c = i % 6;
    *(uint4*)&Qs[r][c * 8] = *(const uint4*)(qp + (long)(q0 + r) * 576 + h * 48 + c * 8);
  }
  for (int i = tid; i < 128; i += 256) {
    int r = i >> 1, c = 6 + (i & 1);
    uint4 z = {0, 0, 0, 0};
    *(uint4*)&Qs[r][c * 8] = z;
  }
  float m[4] = {-1e30f, -1e30f, -1e30f, -1e30f};
  float l[4] = {0.0f, 0.0f, 0.0f, 0.0f};
  f32x4 accO[3] = {};
  const float SC = 0.14433756729740643f; // 1/sqrt(48)
  for (int kc = s * 8; kc < s * 8 + 8; ++kc) {
    int k0 = kc * 64;
    for (int i = tid; i < 384; i += 256) {
      int r = i / 6, c = i % 6;
      *(uint4*)&Ks[r][c * 8] = *(const uint4*)(qp + (long)(k0 + r) * 576 + 192 + h * 48 + c * 8);
    }
    for (int i = tid; i < 128; i += 256) {
      int r = i >> 1, c = 6 + (i & 1);
      uint4 z = {0, 0, 0, 0};
      *(uint4*)&Ks[r][c * 8] = z;
    }
    for (int i = tid; i < 384; i += 256) {  // V from pre-transposed vt: coalesced uint4
      int d = i >> 3, c = i & 7;
      *(uint4*)&Vs[d][c * 8] = *(const uint4*)(vp + (long)d * 1024 + k0 + c * 8);
    }
    __syncthreads();
    f32x4 accS[4] = {};
    bf16x8 a0 = *(const bf16x8*)&Qs[wv * 16 + l16][quad * 8];
    bf16x8 a1 = *(const bf16x8*)&Qs[wv * 16 + l16][32 + quad * 8];
#pragma unroll
    for (int ct = 0; ct < 4; ++ct) {
      bf16x8 b0 = *(const bf16x8*)&Ks[ct * 16 + l16][quad * 8];
      bf16x8 b1 = *(const bf16x8*)&Ks[ct * 16 + l16][32 + quad * 8];
      accS[ct] = __builtin_amdgcn_mfma_f32_16x16x32_bf16(a0, b0, accS[ct], 0, 0, 0);
      accS[ct] = __builtin_amdgcn_mfma_f32_16x16x32_bf16(a1, b1, accS[ct], 0, 0, 0);
    }
#pragma unroll
    for (int r = 0; r < 4; ++r) {
      float s0 = accS[0][r] * SC, s1 = accS[1][r] * SC;
      float s2 = accS[2][r] * SC, s3 = accS[3][r] * SC;
      float mx = fmaxf(fmaxf(s0, s1), fmaxf(s2, s3));
      for (int o = 8; o; o >>= 1) mx = fmaxf(mx, __shfl_xor(mx, o));
      float mn = fmaxf(m[r], mx);
      float alpha = __expf(m[r] - mn);
      float p0 = __expf(s0 - mn), p1 = __expf(s1 - mn);
      float p2 = __expf(s2 - mn), p3 = __expf(s3 - mn);
      float rs = p0 + p1 + p2 + p3;
      for (int o = 8; o; o >>= 1) rs += __shfl_xor(rs, o);
      m[r] = mn;
      l[r] = l[r] * alpha + rs;
      accO[0][r] *= alpha; accO[1][r] *= alpha; accO[2][r] *= alpha;
      int prow = wv * 16 + quad * 4 + r;
      Ps[prow][l16]      = bfr(p0);
      Ps[prow][16 + l16] = bfr(p1);
      Ps[prow][32 + l16] = bfr(p2);
      Ps[prow][48 + l16] = bfr(p3);
    }
    bf16x8 pf0 = *(const bf16x8*)&Ps[wv * 16 + l16][quad * 8];
    bf16x8 pf1 = *(const bf16x8*)&Ps[wv * 16 + l16][32 + quad * 8];
#pragma unroll
    for (int ct = 0; ct < 3; ++ct) {
      bf16x8 v0 = *(const bf16x8*)&Vs[ct * 16 + l16][quad * 8];
      bf16x8 v1 = *(const bf16x8*)&Vs[ct * 16 + l16][32 + quad * 8];
      accO[ct] = __builtin_amdgcn_mfma_f32_16x16x32_bf16(pf0, v0, accO[ct], 0, 0, 0);
      accO[ct] = __builtin_amdgcn_mfma_f32_16x16x32_bf16(pf1, v1, accO[ct], 0, 0, 0);
    }
    __syncthreads();
  }
  long base = (((long)s * 2 + b) * 4 + h) * 1024;
#pragma unroll
  for (int r = 0; r < 4; ++r) {
    int row = q0 + wv * 16 + quad * 4 + r;
#pragma unroll
    for (int ct = 0; ct < 3; ++ct)
      opart[(base + row) * 48 + ct * 16 + l16] = accO[ct][r];
    if (l16 == 0) {
      ml[(base + row) * 2]     = m[r];
      ml[(base + row) * 2 + 1] = l[r];
    }
  }
}

// merge 2 splits: y[b][row][h*48+d] = (O0*e0 + O1*e1) / (l0*e0 + l1*e1)
__global__ void k_attn_merge(const float* __restrict__ opart, const float* __restrict__ ml,
                             bf16* __restrict__ y) {
  int i = blockIdx.x * blockDim.x + threadIdx.x;  // over 2*4*1024*48
  if (i >= 393216) return;
  int d = i % 48;
  int rem = i / 48;            // (b*4+h)*1024 + row
  int row = rem & 1023;
  int bh = rem >> 10;
  int h = bh & 3, b = bh >> 2;
  long i0 = rem;
  long i1 = ((long)(2 + b) * 4 + h) * 1024 + row;
  float m0 = ml[i0 * 2], l0 = ml[i0 * 2 + 1];
  float m1 = ml[i1 * 2], l1 = ml[i1 * 2 + 1];
  float M = fmaxf(m0, m1);
  float e0 = __expf(m0 - M), e1 = __expf(m1 - M);
  float L = l0 * e0 + l1 * e1;
  float o = (opart[i0 * 48 + d] * e0 + opart[i1 * 48 + d] * e1) / L;
  y[(long)b * 1024 * 192 + (long)row * 192 + h * 48 + d] = f2bf(o);
}

// ---------------- EMA: x[pair1] = 0.8*x[pair1] + 0.2*x[pair0] ----------------
__global__ void k_ema(float* __restrict__ x) {
  int i = blockIdx.x * blockDim.x + threadIdx.x;
  if (i < 196608) x[196608 + i] = 0.8f * x[196608 + i] + 0.2f * x[i];
}

// ---------------- fv (2048x2) -> flow [b][2][1024] ----------------
__global__ void k_fv2flow(const float* __restrict__ fv, float* __restrict__ cur) {
  int i = blockIdx.x * blockDim.x + threadIdx.x;
  if (i < 4096) {
    int b = i >> 11, r = i & 2047;
    int c = r >> 10, p = r & 1023;
    cur[i] = fv[(long)(b * 1024 + p) * 2 + c];
  }
}

// ---------------- warp (bilinear, border clamp); img for pair b is imgbase[(b+1)] --------
__global__ void k_warp(const float* __restrict__ imgbase, const float* __restrict__ flow,
                       float* __restrict__ out, int C, int H, int W) {
  int HW = H * W;
  int per = C * HW;
  int i = blockIdx.x * blockDim.x + threadIdx.x;
  if (i >= 2 * per) return;
  int b = i / per;
  int rem = i - b * per;
  int c = rem / HW;
  int p = rem - c * HW;
  int h = p / W, w = p - h * W;
  const float* img = imgbase + (long)(b + 1) * per;
  const float* fl = flow + (long)b * 2 * HW;
  float x = fminf(fmaxf((float)w + fl[p], 0.0f), (float)(W - 1));
  float yy = fminf(fmaxf((float)h + fl[HW + p], 0.0f), (float)(H - 1));
  int x0 = (int)floorf(x), y0 = (int)floorf(yy);
  int x1 = min(x0 + 1, W - 1), y1 = min(y0 + 1, H - 1);
  float wx = x - (float)x0, wy = yy - (float)y0;
  const float* ic = img + (long)c * HW;
  float v00 = ic[y0 * W + x0], v01 = ic[y0 * W + x1];
  float v10 = ic[y1 * W + x0], v11 = ic[y1 * W + x1];
  out[i] = v00 * (1 - wx) * (1 - wy) + v01 * wx * (1 - wy) + v10 * (1 - wx) * wy + v11 * wx * wy;
}

// ---------------- 3x3 conv phase 1: partial sums over an input-channel split -----------
template <int OCG>
__global__ __launch_bounds__(256) void k_conv_part(
    const float* __restrict__ s0, int c0, long s0bs,
    const float* __restrict__ s1, int c1, long s1bs,
    const float* __restrict__ s2, int c2, long s2bs,
    const float* __restrict__ wT, int OC,
    float* __restrict__ pa, long Sa, int na, float* __restrict__ pb,
    int H, int W, int NS) {
  __shared__ float T[8][18][20];
  int tid = threadIdx.x;
  int nTx = W >> 4;
  int ty0 = (blockIdx.x / nTx) << 4, tx0 = (blockIdx.x % nTx) << 4;
  int oc0 = blockIdx.y * OCG;
  int z = blockIdx.z;
  int b = z / NS, s = z - b * NS;
  int ICT = c0 + c1 + c2;
  int csz = (ICT + NS - 1) / NS;
  int g0 = s * csz, g1 = min(ICT, g0 + csz);
  float acc[OCG] = {};
  int ly = tid >> 4, lx = tid & 15;
  const float* sp0 = s0 + (long)b * s0bs;
  const float* sp1 = s1 ? s1 + (long)b * s1bs : nullptr;
  const float* sp2 = s2 ? s2 + (long)b * s2bs : nullptr;
  for (int gc = g0; gc < g1; gc += 8) {
    int nb = min(8, g1 - gc);
    for (int i = tid; i < nb * 324; i += 256) {
      int bch = i / 324, w2 = i - bch * 324;
      int rr = w2 / 18, cc = w2 - rr * 18;
      int yy = ty0 - 1 + rr, xx = tx0 - 1 + cc;
      int gch = gc + bch;
      const float* sp; int lc;
      if (gch < c0) { sp = sp0; lc = gch; }
      else if (gch < c0 + c1) { sp = sp1; lc = gch - c0; }
      else { sp = sp2; lc = gch - c0 - c1; }
      T[bch][rr][cc] = (yy >= 0 && yy < H && xx >= 0 && xx < W)
                           ? sp[(long)lc * H * W + yy * W + xx] : 0.0f;
    }
    __syncthreads();
    for (int j = 0; j < nb; ++j) {
      float t00 = T[j][ly][lx],     t01 = T[j][ly][lx + 1],     t02 = T[j][ly][lx + 2];
      float t10 = T[j][ly + 1][lx], t11 = T[j][ly + 1][lx + 1], t12 = T[j][ly + 1][lx + 2];
      float t20 = T[j][ly + 2][lx], t21 = T[j][ly + 2][lx + 1], t22 = T[j][ly + 2][lx + 2];
      const float* wp = wT + ((long)(gc + j) * OC + oc0) * 9;
#pragma unroll
      for (int o = 0; o < OCG; ++o) {
        const float* w9 = wp + o * 9;
        acc[o] += t00 * w9[0] + t01 * w9[1] + t02 * w9[2]
                + t10 * w9[3] + t11 * w9[4] + t12 * w9[5]
                + t20 * w9[6] + t21 * w9[7] + t22 * w9[8];
      }
    }
    __syncthreads();
  }
  float* base = (s < na) ? pa + (long)s * Sa : pb + (long)(s - na) * Sa;
  long p = (long)(ty0 + ly) * W + (tx0 + lx);
#pragma unroll
  for (int o = 0; o < OCG; ++o)
    base[((long)b * OC + (oc0 + o)) * (long)(H * W) + p] = acc[o];
}

// phase 2: out = [gelu](bias + sum of partial chunks) [+ res]
__global__ void k_conv_fin(const float* __restrict__ pa, long Sa, int na,
                           const float* __restrict__ pb, int nb2,
                           const float* __restrict__ bias, const float* __restrict__ res,
                           float* __restrict__ out, int OC, int HW, int act, int n) {
  int i = blockIdx.x * blockDim.x + threadIdx.x;
  if (i >= n) return;
  int oc = (i / HW) % OC;
  float v = bias[oc];
  for (int s = 0; s < na; ++s) v += pa[(long)s * Sa + i];
  for (int s = 0; s < nb2; ++s) v += pb[(long)s * Sa + i];
  if (act) v = gelu_exact(v);
  if (res) v += res[i];
  out[i] = v;
}

// ---------------- 2x align-corners bilinear upsample ----------------
__global__ void k_upsample(const float* __restrict__ in, float* __restrict__ out) {
  int i = blockIdx.x * blockDim.x + threadIdx.x;
  if (i >= 2 * 2 * 64 * 64) return;
  int p = i & 4095;
  int bc = i >> 12;
  int oy = p >> 6, ox = p & 63;
  float sx = ox * (31.0f / 63.0f), sy = oy * (31.0f / 63.0f);
  int x0 = (int)sx, y0 = (int)sy;
  int x1 = min(x0 + 1, 31), y1 = min(y0 + 1, 31);
  float wx = sx - x0, wy = sy - y0;
  const float* ic = in + (long)bc * 1024;
  out[i] = ic[y0 * 32 + x0] * (1 - wx) * (1 - wy) + ic[y0 * 32 + x1] * wx * (1 - wy)
         + ic[y1 * 32 + x0] * (1 - wx) * wy      + ic[y1 * 32 + x1] * wx * wy;
}

// ---------------- final write (fp32 -> bf16|fp32 per detected dtype) ----------------
__global__ void k_out(const float* __restrict__ cur2, void* __restrict__ out,
                      const int* __restrict__ fl) {
  int isb = *fl;
  int i = blockIdx.x * blockDim.x + threadIdx.x;
  if (i < 16384) {
    if (isb) ((bf16*)out)[i] = f2bf(cur2[i]);
    else ((float*)out)[i] = cur2[i];
  }
}

extern "C" void kernel_launch(void* const* d_in, const int* in_sizes, int n_in,
                              void* d_out, int out_size, void* d_ws, size_t ws_size,
                              hipStream_t stream) {
  const void* feats_l1 = d_in[0];
  const void* feats_l2 = d_in[1];
  const void* tok_w = d_in[3];
  const void* tok_b = d_in[4];
  const void* lcm_ln1_w = d_in[5];
  const void* lcm_ln1_b = d_in[6];
  const void* lcm_in_w  = d_in[7];
  const void* lcm_in_b  = d_in[8];
  const void* lcm_out_w = d_in[9];
  const void* lcm_out_b = d_in[10];
  const void* lcm_ln2_w = d_in[11];
  const void* lcm_ln2_b = d_in[12];
  const void* lcm_mlp_w1 = d_in[13];
  const void* lcm_mlp_b1 = d_in[14];
  const void* lcm_mlp_w2 = d_in[15];
  const void* lcm_mlp_b2 = d_in[16];
  const void* gtr_ln1_w = d_in[17];
  const void* gtr_ln1_b = d_in[18];
  const void* gtr_in_w  = d_in[19];
  const void* gtr_in_b  = d_in[20];
  const void* gtr_out_w = d_in[21];
  const void* gtr_out_b = d_in[22];
  const void* gtr_ln2_w = d_in[23];
  const void* gtr_ln2_b = d_in[24];
  const void* gtr_mlp_w1 = d_in[25];
  const void* gtr_mlp_b1 = d_in[26];
  const void* gtr_mlp_w2 = d_in[27];
  const void* gtr_mlp_b2 = d_in[28];
  const void* head_w1 = d_in[29];
  const void* head_b1 = d_in[30];
  const void* head_w2 = d_in[31];
  const void* head_b2 = d_in[32];
  const void* ref1_w1 = d_in[33];
  const void* ref1_b1 = d_in[34];
  const void* ref1_w2 = d_in[35];
  const void* ref1_b2 = d_in[36];
  const void* ref0_w1 = d_in[37];
  const void* ref0_b1 = d_in[38];
  const void* ref0_w2 = d_in[39];
  const void* ref0_b2 = d_in[40];
  (void)ws_size; (void)n_in; (void)in_sizes; (void)out_size;

  // ---- workspace layout (fp32; ~17.3 MB, unchanged budget) ----
  int* flag = (int*)d_ws;
  int* oneflag = (int*)d_ws + 2;
  float* wsf = (float*)d_ws;
  float* F2  = wsf + 16;              // 393216
  float* F1  = F2 + 393216;           // 786432 : feats_l1 fp32 (decoder) / attn O-partials (transformer)
  float* x   = F1 + 786432;           // 393216 (fp32 residual stream)
  float* ta  = x + 393216;            // 393216 (bf16 LN out | attn m/l | fp32 head-hidden)
  float* yb  = ta + 393216;           // 393216 (bf16 attention out)
  float* big = yb + 393216;           // 1572864: corrT/qkv/vt/hid (bf16) | decoder scratch
  float* fv  = big + 1572864;         // 4096
  float* cur = fv + 4096;             // 4096   [2][2][1024]
  float* cur2 = cur + 4096;           // 16384  [2][2][4096]
  float* cwT1a = cur2 + 16384;        // 297216 : ref1_w1 fp32 transposed [258][128][9]
  float* cb1a  = cwT1a + 297216;      // 128
  float* cwT1b = cb1a + 128;          // 2304   : ref1_w2 [128][2][9]
  float* cb1b  = cwT1b + 2304;        // 16 (2 used)
  float* cwT0a = cb1b + 16;           // 74880  : ref0_w1 [130][64][9]
  float* cb0a  = cwT0a + 74880;       // 64
  float* cwT0b = cb0a + 64;           // 1152   : ref0_w2 [64][2][9]
  float* cb0b  = cwT0b + 1152;        // 16 (2 used)
  bf16* wtok   = (bf16*)(cb0b + 16);  // 12288 bf16: padded tokenizer W [192][64]
  bf16* tb      = (bf16*)ta;          // LN output, 2048x192 bf16
  bf16* ybb     = (bf16*)yb;          // attention out, 2048x192 bf16
  bf16* corrTb  = (bf16*)big;         // 2048x64 bf16
  bf16* qkvbb   = (bf16*)big;         // 2048x576 bf16 (589824 float-equiv)
  bf16* vtb     = (bf16*)(big + 655360); // V transposed [2][4][48][1024] bf16 (196608 f-eq)
  bf16* hidb    = (bf16*)big;         // 2048x768 bf16 (qkv dead by then)
  float* opart = F1;                  // [2 splits][2][4][1024][48] = 786432 floats exact
  float* mlbuf = ta;                  // [2 splits][2][4][1024][2] = 32768 floats
  float* wp1  = big;                  // [2][128][1024]
  float* mid1 = big + 262144;         // [2][128][1024]
  float* wp0  = big;                  // [2][64][4096]
  float* mid0 = big + 524288;         // [2][64][4096]
  float* bigtail = big + 1048576;     // 3rd l0-conv1 partial chunk
  float* p1b  = big + 524288;         // l1-conv2 partials

  k_detect<<<1, 256, 0, stream>>>((const unsigned short*)feats_l1, flag);
  k_setone<<<1, 1, 0, stream>>>(oneflag);
  k_cvt<<<1536, 256, 0, stream>>>(feats_l2, F2, 393216, flag);
  // NOTE: feats_l1 -> F1 conversion deferred until decoder (F1 region = attn partials now)
  k_cvt_trans<<<1161, 256, 0, stream>>>(ref1_w1, cwT1a, 128, 258, 297216, flag);
  k_cvt<<<1, 256, 0, stream>>>(ref1_b1, cb1a, 128, flag);
  k_cvt_trans<<<9, 256, 0, stream>>>(ref1_w2, cwT1b, 2, 128, 2304, flag);
  k_cvt<<<1, 256, 0, stream>>>(ref1_b2, cb1b, 2, flag);
  k_cvt_trans<<<293, 256, 0, stream>>>(ref0_w1, cwT0a, 64, 130, 74880, flag);
  k_cvt<<<1, 256, 0, stream>>>(ref0_b1, cb0a, 64, flag);
  k_cvt_trans<<<5, 256, 0, stream>>>(ref0_w2, cwT0b, 2, 64, 1152, flag);
  k_cvt<<<1, 256, 0, stream>>>(ref0_b2, cb0b, 2, flag);
  k_padtokw<<<48, 256, 0, stream>>>(tok_w, wtok, flag);

  // ---- tokens (level 1 only): corr (bf16, K padded 64) then tokenizer GEMM (MFMA) ----
  k_corr<<<dim3(1024, 2), 64, 0, stream>>>(F2, corrTb);
  k_gemm_mfma<0, false, 1, 0><<<dim3(3, 32), 256, 0, stream>>>(
      corrTb, wtok, 0, tok_b, 192, flag, nullptr, x, 2048, 192, 64, oneflag);

  auto run_block = [&](const void* ln1w, long o1, const void* ln1b, long o2,
                       const void* inw, long o3, const void* inb, long o4,
                       const void* ow, long o5, const void* ob, long o6,
                       const void* ln2w, long o7, const void* ln2b, long o8,
                       const void* w1, long o9, const void* b1, long o10,
                       const void* w2, long o11, const void* b2, long o12) {
    k_ln<<<512, 256, 0, stream>>>(x, tb, ln1w, o1, ln1b, o2, flag);
    k_gemm_mfma<0, false, 1, 1><<<dim3(9, 32), 256, 0, stream>>>(
        tb, inw, o3, inb, o4, flag, nullptr, qkvbb, 2048, 576, 192, flag);
    k_vt<<<dim3(16, 4, 2), 256, 0, stream>>>(qkvbb, vtb);
    k_attn_mfma<<<dim3(32, 4, 2), 256, 0, stream>>>(qkvbb, vtb, opart, mlbuf);
    k_attn_merge<<<1536, 256, 0, stream>>>(opart, mlbuf, ybb);
    k_gemm_mfma<0, true, 1, 0><<<dim3(3, 32), 256, 0, stream>>>(
        ybb, ow, o5, ob, o6, flag, x, x, 2048, 192, 192, flag);
    k_ln<<<512, 256, 0, stream>>>(x, tb, ln2w, o7, ln2b, o8, flag);
    k_gemm_mfma<1, false, 1, 1><<<dim3(12, 32), 256, 0, stream>>>(
        tb, w1, o9, b1, o10, flag, nullptr, hidb, 2048, 768, 192, flag);
    k_gemm_mfma<0, true, 1, 0><<<dim3(3, 32), 256, 0, stream>>>(
        hidb, w2, o11, b2, o12, flag, x, x, 2048, 192, 768, flag);
  };

  // ---- LCM: 6 blocks, both pairs batched ----
  for (int i = 0; i < 6; ++i) {
    run_block(lcm_ln1_w, (long)i * 192, lcm_ln1_b, (long)i * 192,
              lcm_in_w, (long)i * 110592, lcm_in_b, (long)i * 576,
              lcm_out_w, (long)i * 36864, lcm_out_b, (long)i * 192,
              lcm_ln2_w, (long)i * 192, lcm_ln2_b, (long)i * 192,
              lcm_mlp_w1, (long)i * 147456, lcm_mlp_b1, (long)i * 768,
              lcm_mlp_w2, (long)i * 147456, lcm_mlp_b2, (long)i * 192);
  }
  k_ema<<<768, 256, 0, stream>>>(x);

  // ---- GTR: 2 blocks ----
  for (int i = 0; i < 2; ++i) {
    run_block(gtr_ln1_w, (long)i * 192, gtr_ln1_b, (long)i * 192,
              gtr_in_w, (long)i * 110592, gtr_in_b, (long)i * 576,
              gtr_out_w, (long)i * 36864, gtr_out_b, (long)i * 192,
              gtr_ln2_w, (long)i * 192, gtr_ln2_b, (long)i * 192,
              gtr_mlp_w1, (long)i * 147456, gtr_mlp_b1, (long)i * 768,
              gtr_mlp_w2, (long)i * 147456, gtr_mlp_b2, (long)i * 192);
  }

  // ---- head -> coarse flow ----
  k_gemm_mfma<1, false, 0, 0><<<dim3(3, 32), 256, 0, stream>>>(
      x, head_w1, 0, head_b1, 0, flag, nullptr, ta, 2048, 192, 192, flag);
  k_gemm<0, false><<<dim3(1, 16), 256, 0, stream>>>(ta, head_w2, 0, head_b2, 0, nullptr, fv,
                                                    2048, 2, 192, 192, flag);
  k_fv2flow<<<16, 256, 0, stream>>>(fv, cur);

  // F1 now free of attention partials -> stage feats_l1 fp32 for the decoder
  k_cvt<<<3072, 256, 0, stream>>>(feats_l1, F1, 786432, flag);

  // ---- decoder level 1 (32x32, feats_l2); IC=258 split NS=4 ----
  for (int it = 0; it < 4; ++it) {
    k_warp<<<1024, 256, 0, stream>>>(F2, cur, wp1, 128, 32, 32);
    k_conv_part<8><<<dim3(4, 16, 8), 256, 0, stream>>>(
        F2, 128, 131072, cur, 2, 2048, wp1, 128, 131072,
        cwT1a, 128, x, 262144, 4, nullptr, 32, 32, 4);
    k_conv_fin<<<1024, 256, 0, stream>>>(x, 262144, 4, nullptr, 0, cb1a, nullptr,
                                         mid1, 128, 1024, 1, 262144);
    k_conv_part<2><<<dim3(4, 1, 32), 256, 0, stream>>>(
        mid1, 128, 131072, nullptr, 0, 0, nullptr, 0, 0,
        cwT1b, 2, p1b, 4096, 16, nullptr, 32, 32, 16);
    k_conv_fin<<<32, 256, 0, stream>>>(p1b, 4096, 16, nullptr, 0, cb1b, cur,
                                       cur, 2, 1024, 0, 8192);
  }
  k_upsample<<<64, 256, 0, stream>>>(cur, cur2);

  // ---- decoder level 0 (64x64, feats_l1); IC=130 split NS=3 ----
  for (int it = 0; it < 4; ++it) {
    k_warp<<<2048, 256, 0, stream>>>(F1, cur2, wp0, 64, 64, 64);
    k_conv_part<8><<<dim3(16, 8, 6), 256, 0, stream>>>(
        F1, 64, 262144, cur2, 2, 8192, wp0, 64, 262144,
        cwT0a, 64, x, 524288, 2, bigtail, 64, 64, 3);
    k_conv_fin<<<2048, 256, 0, stream>>>(x, 524288, 2, bigtail, 1, cb0a, nullptr,
                                         mid0, 64, 4096, 1, 524288);
    k_conv_part<2><<<dim3(16, 1, 16), 256, 0, stream>>>(
        mid0, 64, 262144, nullptr, 0, 0, nullptr, 0, 0,
        cwT0b, 2, x, 16384, 8, nullptr, 64, 64, 8);
    k_conv_fin<<<128, 256, 0, stream>>>(x, 16384, 8, nullptr, 0, cb0b, cur2,
                                        cur2, 2, 4096, 0, 32768);
  }

  k_out<<<64, 256, 0, stream>>>(cur2, d_out, flag);
}